// Round 1
// baseline (40.916 us; speedup 1.0000x reference)
//
#include <hip/hip_runtime.h>
#include <hip/hip_bf16.h>

#define B 4
#define S 2048
#define D 512
#define P 16
#define NC 64   // chunks over sequence
#define CL 32   // chunk length = S/NC

// ---------------------------------------------------------------------------
// Kernel 1: prods[b,s,p] = dot(proxy[p,:], x[b,s,:]); w[b,s,p] = softmax_p(prods/4)
// One wave (64 lanes) per (b,s). Lane owns 8 contiguous d. Butterfly reduce.
// ---------------------------------------------------------------------------
__global__ __launch_bounds__(256) void k_prods(const float* __restrict__ x,
                                               const float* __restrict__ proxy,
                                               float* __restrict__ prods,
                                               float* __restrict__ wgt) {
    int wid  = (blockIdx.x * blockDim.x + threadIdx.x) >> 6;  // bs index 0..B*S-1
    int lane = threadIdx.x & 63;
    if (wid >= B * S) return;

    const float* xr = x + (size_t)wid * D + lane * 8;
    float4 xa = *(const float4*)xr;
    float4 xb = *(const float4*)(xr + 4);

    float part[P];
#pragma unroll
    for (int p = 0; p < P; ++p) {
        const float* pr = proxy + p * D + lane * 8;
        float4 pa = *(const float4*)pr;
        float4 pb = *(const float4*)(pr + 4);
        part[p] = xa.x*pa.x + xa.y*pa.y + xa.z*pa.z + xa.w*pa.w
                + xb.x*pb.x + xb.y*pb.y + xb.z*pb.z + xb.w*pb.w;
    }
    // butterfly reduce each p across the 64-lane wave (result broadcast to all lanes)
#pragma unroll
    for (int p = 0; p < P; ++p) {
        float v = part[p];
#pragma unroll
        for (int off = 32; off > 0; off >>= 1) v += __shfl_xor(v, off);
        part[p] = v;
    }
    // softmax over p of part/4
    float m = part[0];
#pragma unroll
    for (int p = 1; p < P; ++p) m = fmaxf(m, part[p]);
    float e[P];
    float den = 0.f;
#pragma unroll
    for (int p = 0; p < P; ++p) { e[p] = __expf((part[p] - m) * 0.25f); den += e[p]; }
    float inv = 1.f / den;

    // select this lane's value with a constant-index cndmask chain (no scratch)
    int lp = lane & 15;
    float myp = part[0], mye = e[0];
#pragma unroll
    for (int p = 1; p < P; ++p) {
        bool sel = (lp == p);
        myp = sel ? part[p] : myp;
        mye = sel ? e[p]    : mye;
    }
    if (lane < P) {
        prods[(size_t)wid * P + lane] = myp;
        wgt  [(size_t)wid * P + lane] = mye * inv;
    }
}

// ---------------------------------------------------------------------------
// Kernel 2: chunk totals T[b,c,p,d] = sum_{s in chunk c} prods[b,s,p]*x[b,s,d]
// Block = (b,c), 512 threads, thread = d.
// ---------------------------------------------------------------------------
__global__ __launch_bounds__(512) void k_totals(const float* __restrict__ x,
                                                const float* __restrict__ prods,
                                                float* __restrict__ T) {
    int c = blockIdx.x & (NC - 1);
    int b = blockIdx.x >> 6;
    int d = threadIdx.x;

    float acc[P];
#pragma unroll
    for (int p = 0; p < P; ++p) acc[p] = 0.f;

    int bs0 = b * S + c * CL;
#pragma unroll 4
    for (int i = 0; i < CL; ++i) {
        int bs = bs0 + i;
        float xv = x[(size_t)bs * D + d];
        const float4* pp = (const float4*)(prods + (size_t)bs * P);
        float pr[P];
        ((float4*)pr)[0] = pp[0];
        ((float4*)pr)[1] = pp[1];
        ((float4*)pr)[2] = pp[2];
        ((float4*)pr)[3] = pp[3];
#pragma unroll
        for (int p = 0; p < P; ++p) acc[p] = fmaf(pr[p], xv, acc[p]);
    }
    size_t tb = ((size_t)(b * NC + c)) * (P * D) + d;
#pragma unroll
    for (int p = 0; p < P; ++p) T[tb + p * D] = acc[p];
}

// ---------------------------------------------------------------------------
// Kernel 3: in-place exclusive prefix over chunks: T[b,c,p,d] <- sum_{c'<c} T[b,c',p,d]
// Thread = (b,p,d); each thread owns its lane across all 64 chunks.
// ---------------------------------------------------------------------------
__global__ __launch_bounds__(256) void k_scan(float* __restrict__ T) {
    int t = blockIdx.x * blockDim.x + threadIdx.x;   // ((b*P+p)*D + d)
    int d = t & (D - 1);
    int p = (t >> 9) & (P - 1);
    int b = t >> 13;
    size_t base = ((size_t)b * NC * P + p) * D + d;
    float run = 0.f;
#pragma unroll 8
    for (int c = 0; c < NC; ++c) {
        size_t idx = base + (size_t)c * (P * D);
        float v = T[idx];
        T[idx] = run;
        run += v;
    }
}

// ---------------------------------------------------------------------------
// Kernel 4: apply. Block = (b,c), thread = d. State seeded from exclusive prefix,
// then the 32-step in-chunk scan with fused softmax-weighted output.
// ---------------------------------------------------------------------------
__global__ __launch_bounds__(512) void k_apply(const float* __restrict__ x,
                                               const float* __restrict__ prods,
                                               const float* __restrict__ wgt,
                                               const float* __restrict__ T,
                                               float* __restrict__ out) {
    int c = blockIdx.x & (NC - 1);
    int b = blockIdx.x >> 6;
    int d = threadIdx.x;

    float st[P];
    size_t tb = ((size_t)(b * NC + c)) * (P * D) + d;
#pragma unroll
    for (int p = 0; p < P; ++p) st[p] = T[tb + p * D];

    int bs0 = b * S + c * CL;
#pragma unroll 2
    for (int i = 0; i < CL; ++i) {
        int bs = bs0 + i;
        float xv = x[(size_t)bs * D + d];
        const float4* pp = (const float4*)(prods + (size_t)bs * P);
        const float4* wp = (const float4*)(wgt   + (size_t)bs * P);
        float pr[P], ww[P];
        ((float4*)pr)[0] = pp[0];
        ((float4*)pr)[1] = pp[1];
        ((float4*)pr)[2] = pp[2];
        ((float4*)pr)[3] = pp[3];
        ((float4*)ww)[0] = wp[0];
        ((float4*)ww)[1] = wp[1];
        ((float4*)ww)[2] = wp[2];
        ((float4*)ww)[3] = wp[3];
        float o = 0.f;
#pragma unroll
        for (int p = 0; p < P; ++p) {
            st[p] = fmaf(pr[p], xv, st[p]);
            o = fmaf(ww[p], st[p], o);
        }
        out[(size_t)bs * D + d] = o;
    }
}

extern "C" void kernel_launch(void* const* d_in, const int* in_sizes, int n_in,
                              void* d_out, int out_size, void* d_ws, size_t ws_size,
                              hipStream_t stream) {
    const float* x     = (const float*)d_in[0];
    const float* proxy = (const float*)d_in[1];
    float* out   = (float*)d_out;

    float* prods = (float*)d_ws;                 // B*S*P floats = 512 KiB
    float* wgt   = prods + (size_t)B * S * P;    // 512 KiB
    float* T     = wgt   + (size_t)B * S * P;    // B*NC*P*D floats = 8 MiB

    k_prods <<<(B * S) / 4, 256, 0, stream>>>(x, proxy, prods, wgt);
    k_totals<<<B * NC,     512, 0, stream>>>(x, prods, T);
    k_scan  <<<(B * P * D) / 256, 256, 0, stream>>>(T);
    k_apply <<<B * NC,     512, 0, stream>>>(x, prods, wgt, T, out);
}